// Round 7
// baseline (251.774 us; speedup 1.0000x reference)
//
#include <hip/hip_runtime.h>
#include <hip/hip_bf16.h>
#include <math.h>

typedef __attribute__((ext_vector_type(8))) short short8;
typedef __attribute__((ext_vector_type(4))) short short4v;
typedef __attribute__((ext_vector_type(4))) float f32x4;

static __device__ __forceinline__ short f2bf(float f) {
  union { float f; unsigned u; } x;
  x.f = f;
  unsigned r = x.u + 0x7fffu + ((x.u >> 16) & 1u);
  return (short)(r >> 16);
}

#define GLD16(g, l)                                                   \
  __builtin_amdgcn_global_load_lds(                                   \
      (const __attribute__((address_space(1))) void*)(g),             \
      (__attribute__((address_space(3))) void*)(l), 16, 0, 0)
#define BAR() asm volatile("s_barrier" ::: "memory")
#define VMCNT8() asm volatile("s_waitcnt vmcnt(8)" ::: "memory")
#define VMCNT4() asm volatile("s_waitcnt vmcnt(4)" ::: "memory")
#define VMCNT0() asm volatile("s_waitcnt vmcnt(0)" ::: "memory")

__global__ __launch_bounds__(256) void cvt_f32_bf16(const float* __restrict__ in,
                                                    short* __restrict__ out, int n8) {
  int i = blockIdx.x * 256 + threadIdx.x;
  if (i >= n8) return;
  const float4* p = (const float4*)in + (size_t)i * 2;
  float4 a = p[0], b = p[1];
  short8 o;
  o[0] = f2bf(a.x); o[1] = f2bf(a.y); o[2] = f2bf(a.z); o[3] = f2bf(a.w);
  o[4] = f2bf(b.x); o[5] = f2bf(b.y); o[6] = f2bf(b.z); o[7] = f2bf(b.w);
  *((short8*)out + i) = o;
}

// ---------------------------------------------------------------------------
// C = A * B^T, bf16 MFMA 16x16x32. BM=BN=256, BK=32, 512 threads (8 waves
// 2M x 4N, wave tile 128x64: M_rep=8, N_rep=4). QUAD-buffered LDS (128 KB),
// 2 phases per K-tile (16 MFMA each), stage tile t+3 one-(A|B)-tile/phase,
// vmcnt(8) once per K-tile: tiles t+2,t+3 stay in flight, t+1 drained just
// in time. XOR swizzle slot^=(row&3) on both stage-source and ds_read.
// MODE 2: C fp32 = acc*scale + rel_bias[gc-gr+ml-1] (scores)
// MODE 3: C fp32 = acc (PV)
// MODE 4: fused QKV: 1024-col slice 0 -> Q bf16, 1 -> K bf16, 2 -> V^T
// ---------------------------------------------------------------------------
template <int MODE>
__global__ __launch_bounds__(512) void gemm4b(
    const short* __restrict__ A, const short* __restrict__ Bt,
    void* __restrict__ C0, void* __restrict__ C1, void* __restrict__ C2,
    const float* __restrict__ rel_bias,
    int N, int K, long aZ, long bZ, long cZ, int Cdim, float scale, int ml) {
  __shared__ short sA[4][256 * 32];
  __shared__ short sB[4][256 * 32];
  const int tid = threadIdx.x, lane = tid & 63, wid = tid >> 6;
  const int z = blockIdx.z;
  const short* Az = A + (size_t)z * aZ;
  const short* Bz = Bt + (size_t)z * bZ;
  const int brow = blockIdx.x * 256, bcol = blockIdx.y * 256;
  const int wr = wid >> 2, wc = wid & 3;
  const int lrow = lane & 15, kg = lane >> 4;

  // staging: step s covers rows s*128..+127; wave covers 16 rows, 4 lanes/row
  const int srow = wid * 16 + (lane >> 2);           // row within step
  const int scol = ((lane & 3) ^ ((lane >> 2) & 3)) * 8;  // swizzled src col
  const short* aSrc0 = Az + (size_t)(brow + srow) * K + scol;
  const short* aSrc1 = Az + (size_t)(brow + 128 + srow) * K + scol;
  const short* bSrc0 = Bz + (size_t)(bcol + srow) * K + scol;
  const short* bSrc1 = Bz + (size_t)(bcol + 128 + srow) * K + scol;
  const int d0 = wid * 512, d1 = 4096 + wid * 512;   // LDS dest (shorts)

  // ds_read: logical k-slot kg, physical slot kg^(row&3); row&3 == lrow&3
  const int kOff = (kg ^ (lrow & 3)) * 8;
  const int aBase = (wr * 128 + lrow) * 32 + kOff;   // + m*512
  const int bBase = (wc * 64 + lrow) * 32 + kOff;    // + n*512

  short8 a[4], b[4];
  f32x4 acc[8][4] = {};

  short *pa0 = &sA[0][0], *pa1 = &sA[1][0], *pa2 = &sA[2][0], *pa3 = &sA[3][0];
  short *pb0 = &sB[0][0], *pb1 = &sB[1][0], *pb2 = &sB[2][0], *pb3 = &sB[3][0];

#define STG_A(P, T)                                   \
  do {                                                \
    GLD16(aSrc0 + (size_t)(T) * 32, (P) + d0);        \
    GLD16(aSrc1 + (size_t)(T) * 32, (P) + d1);        \
  } while (0)
#define STG_B(P, T)                                   \
  do {                                                \
    GLD16(bSrc0 + (size_t)(T) * 32, (P) + d0);        \
    GLD16(bSrc1 + (size_t)(T) * 32, (P) + d1);        \
  } while (0)
#define RD_A(P, MH)                                                 \
  do {                                                              \
    _Pragma("unroll") for (int m = 0; m < 4; ++m)                   \
        a[m] = *(const short8*)&(P)[aBase + ((MH)*4 + m) * 512];    \
  } while (0)
#define RD_B(P)                                                     \
  do {                                                              \
    _Pragma("unroll") for (int n = 0; n < 4; ++n)                   \
        b[n] = *(const short8*)&(P)[bBase + n * 512];               \
  } while (0)
#define MFMA16(MH)                                                            \
  do {                                                                        \
    __builtin_amdgcn_s_setprio(1);                                            \
    _Pragma("unroll") for (int m = 0; m < 4; ++m)                             \
        _Pragma("unroll") for (int n = 0; n < 4; ++n)                         \
            acc[(MH)*4 + m][n] = __builtin_amdgcn_mfma_f32_16x16x32_bf16(     \
                a[m], b[n], acc[(MH)*4 + m][n], 0, 0, 0);                     \
    __builtin_amdgcn_s_setprio(0);                                            \
  } while (0)
#define ROT()                                                    \
  do {                                                           \
    short* q;                                                    \
    q = pa0; pa0 = pa1; pa1 = pa2; pa2 = pa3; pa3 = q;           \
    q = pb0; pb0 = pb1; pb1 = pb2; pb2 = pb3; pb3 = q;           \
  } while (0)

  // prologue: stage tiles 0,1,2 (12 loads); keep tiles 1,2 (8) in flight
  STG_A(pa0, 0); STG_B(pb0, 0);
  STG_A(pa1, 1); STG_B(pb1, 1);
  STG_A(pa2, 2); STG_B(pb2, 2);
  VMCNT8();
  BAR();

  const int NT = K >> 5;  // K/32 tiles (>= 32 here)
  for (int t = 0; t < NT - 3; ++t) {
    // P0: read a(m0-3)+b, stage A(t+3)
    RD_A(pa0, 0); RD_B(pb0);
    STG_A(pa3, t + 3);
    BAR(); MFMA16(0); BAR();
    // P1: read a(m4-7), stage B(t+3); vmcnt(8) drains tile t+1's stages
    RD_A(pa0, 1);
    STG_B(pb3, t + 3);
    VMCNT8();
    BAR(); MFMA16(1); BAR();
    ROT();
  }
  // t = NT-3: no staging; drain tile NT-2 (keep NT-1's 4)
  RD_A(pa0, 0); RD_B(pb0);
  BAR(); MFMA16(0); BAR();
  RD_A(pa0, 1);
  VMCNT4();
  BAR(); MFMA16(1); BAR();
  ROT();
  // t = NT-2: drain tile NT-1
  RD_A(pa0, 0); RD_B(pb0);
  BAR(); MFMA16(0); BAR();
  RD_A(pa0, 1);
  VMCNT0();
  BAR(); MFMA16(1); BAR();
  ROT();
  // t = NT-1
  RD_A(pa0, 0); RD_B(pb0);
  BAR(); MFMA16(0); BAR();
  RD_A(pa0, 1);
  BAR(); MFMA16(1);

  // epilogue
#pragma unroll
  for (int m = 0; m < 8; ++m) {
#pragma unroll
    for (int n = 0; n < 4; ++n) {
#pragma unroll
      for (int r = 0; r < 4; ++r) {
        float v = acc[m][n][r];
        int gr = brow + wr * 128 + m * 16 + kg * 4 + r;
        int gc = bcol + wc * 64 + n * 16 + lrow;
        if constexpr (MODE == 2) {
          int idx = gc - gr + (ml - 1);
          idx = min(max(idx, 0), 2 * ml - 2);
          ((float*)C0 + (size_t)z * cZ)[(size_t)gr * N + gc] =
              v * scale + rel_bias[idx];
        } else if constexpr (MODE == 3) {
          ((float*)C0 + (size_t)z * cZ)[(size_t)gr * N + gc] = v;
        } else {  // MODE 4: fused QKV, 1024-col slices
          int s = gc >> 10, cc = gc & 1023;
          if (s == 0) {
            ((short*)C0)[(size_t)gr * 1024 + cc] = f2bf(v);
          } else if (s == 1) {
            ((short*)C1)[(size_t)gr * 1024 + cc] = f2bf(v);
          } else {
            int b_ = gr / Cdim, c_ = gr % Cdim;
            ((short*)C2)[((size_t)b_ * 1024 + cc) * Cdim + c_] = f2bf(v);
          }
        }
      }
    }
  }
#undef STG_A
#undef STG_B
#undef RD_A
#undef RD_B
#undef MFMA16
#undef ROT
}

// Row softmax in place (rows of 2048) + bf16 copy for the PV GEMM.
__global__ __launch_bounds__(256) void softmax_rows(float* __restrict__ w,
                                                    short* __restrict__ wb, int Cd) {
  const size_t row = blockIdx.x;
  float4* p = (float4*)(w + row * (size_t)Cd);
  const int tid = threadIdx.x;
  float4 v0 = p[tid];
  float4 v1 = p[tid + 256];
  float mx = fmaxf(fmaxf(fmaxf(v0.x, v0.y), fmaxf(v0.z, v0.w)),
                   fmaxf(fmaxf(v1.x, v1.y), fmaxf(v1.z, v1.w)));
#pragma unroll
  for (int o = 32; o; o >>= 1) mx = fmaxf(mx, __shfl_xor(mx, o));
  __shared__ float red[8];
  const int wv = tid >> 6;
  if ((tid & 63) == 0) red[wv] = mx;
  __syncthreads();
  mx = fmaxf(fmaxf(red[0], red[1]), fmaxf(red[2], red[3]));
  v0.x = __expf(v0.x - mx); v0.y = __expf(v0.y - mx);
  v0.z = __expf(v0.z - mx); v0.w = __expf(v0.w - mx);
  v1.x = __expf(v1.x - mx); v1.y = __expf(v1.y - mx);
  v1.z = __expf(v1.z - mx); v1.w = __expf(v1.w - mx);
  float s = v0.x + v0.y + v0.z + v0.w + v1.x + v1.y + v1.z + v1.w;
#pragma unroll
  for (int o = 32; o; o >>= 1) s += __shfl_xor(s, o);
  if ((tid & 63) == 0) red[4 + wv] = s;
  __syncthreads();
  s = red[4] + red[5] + red[6] + red[7];
  float inv = 1.0f / s;
  v0.x *= inv; v0.y *= inv; v0.z *= inv; v0.w *= inv;
  v1.x *= inv; v1.y *= inv; v1.z *= inv; v1.w *= inv;
  p[tid] = v0;
  p[tid + 256] = v1;
  short4v b0, b1;
  b0[0] = f2bf(v0.x); b0[1] = f2bf(v0.y); b0[2] = f2bf(v0.z); b0[3] = f2bf(v0.w);
  b1[0] = f2bf(v1.x); b1[1] = f2bf(v1.y); b1[2] = f2bf(v1.z); b1[3] = f2bf(v1.w);
  short* wrow = wb + row * (size_t)Cd;
  *(short4v*)&wrow[tid * 4] = b0;
  *(short4v*)&wrow[1024 + tid * 4] = b1;
}

extern "C" void kernel_launch(void* const* d_in, const int* in_sizes, int n_in,
                              void* d_out, int out_size, void* d_ws, size_t ws_size,
                              hipStream_t stream) {
  const float* x = (const float*)d_in[0];
  const float* Wq = (const float*)d_in[1];
  const float* Wk = (const float*)d_in[2];
  const float* Wv = (const float*)d_in[3];
  const float* rb = (const float*)d_in[4];

  const int E = 1024;
  const int Mt = in_sizes[0] / E;           // B*C = 8192
  const int Cd = out_size / Mt - E;         // 2048
  const int B = Mt / Cd;                    // 4
  const int ml = (in_sizes[4] + 1) / 2;     // max_len = 2048
  const float scale = 1.0f / sqrtf((float)E);

  // workspace layout (bf16 = short)
  short* xb = (short*)d_ws;                 // Mt*E
  short* wqb = xb + (size_t)Mt * E;         // E*E (Wq,Wk,Wv contiguous = 3072xE)
  short* wkb = wqb + (size_t)E * E;
  short* wvb = wkb + (size_t)E * E;
  short* Qb = wvb + (size_t)E * E;          // Mt*E
  short* Kb = Qb + (size_t)Mt * E;          // Mt*E
  short* Vt = Kb + (size_t)Mt * E;          // B*E*Cd
  short* wbf = Qb;                          // Mt*Cd (reuse Q+K after scores)

  float* outp = (float*)d_out;              // Mt*E
  float* wts = outp + (size_t)Mt * E;       // Mt*Cd

  cvt_f32_bf16<<<(Mt * E) / 2048, 256, 0, stream>>>(x, xb, (Mt * E) / 8);
  cvt_f32_bf16<<<(E * E) / 2048, 256, 0, stream>>>(Wq, wqb, (E * E) / 8);
  cvt_f32_bf16<<<(E * E) / 2048, 256, 0, stream>>>(Wk, wkb, (E * E) / 8);
  cvt_f32_bf16<<<(E * E) / 2048, 256, 0, stream>>>(Wv, wvb, (E * E) / 8);

  dim3 blk(512);
  // fused QKV projection: A = xb (8192x1024), Bt = [Wq;Wk;Wv] (3072x1024)
  gemm4b<4><<<dim3(Mt / 256, 3 * E / 256, 1), blk, 0, stream>>>(
      xb, wqb, Qb, Kb, Vt, nullptr, 3 * E, E, 0, 0, 0, Cd, 0.f, ml);
  // scores = Q K^T * scale + bias (fp32 into weights region)
  gemm4b<2><<<dim3(Cd / 256, Cd / 256, B), blk, 0, stream>>>(
      Qb, Kb, wts, nullptr, nullptr, rb, Cd, E, (long)Cd * E, (long)Cd * E,
      (long)Cd * Cd, Cd, scale, ml);
  softmax_rows<<<Mt, 256, 0, stream>>>(wts, wbf, Cd);
  // out = weights @ V (A = bf16 weights, Bt = V^T)
  gemm4b<3><<<dim3(Cd / 256, E / 256, B), blk, 0, stream>>>(
      wbf, Vt, outp, nullptr, nullptr, nullptr, E, Cd, (long)Cd * Cd,
      (long)E * Cd, (long)Cd * E, Cd, 0.f, ml);
}

// Round 8
// 222.103 us; speedup vs baseline: 1.1336x; 1.1336x over previous
//
#include <hip/hip_runtime.h>
#include <hip/hip_bf16.h>
#include <math.h>

typedef __attribute__((ext_vector_type(8))) short short8;
typedef __attribute__((ext_vector_type(4))) short short4v;
typedef __attribute__((ext_vector_type(4))) float f32x4;

static __device__ __forceinline__ short f2bf(float f) {
  union { float f; unsigned u; } x;
  x.f = f;
  unsigned r = x.u + 0x7fffu + ((x.u >> 16) & 1u);
  return (short)(r >> 16);
}

#define GLD16(g, l)                                                   \
  __builtin_amdgcn_global_load_lds(                                   \
      (const __attribute__((address_space(1))) void*)(g),             \
      (__attribute__((address_space(3))) void*)(l), 16, 0, 0)
#define BAR() asm volatile("s_barrier" ::: "memory")

__global__ __launch_bounds__(256) void cvt_f32_bf16(const float* __restrict__ in,
                                                    short* __restrict__ out, int n8) {
  int i = blockIdx.x * 256 + threadIdx.x;
  if (i >= n8) return;
  const float4* p = (const float4*)in + (size_t)i * 2;
  float4 a = p[0], b = p[1];
  short8 o;
  o[0] = f2bf(a.x); o[1] = f2bf(a.y); o[2] = f2bf(a.z); o[3] = f2bf(a.w);
  o[4] = f2bf(b.x); o[5] = f2bf(b.y); o[6] = f2bf(b.z); o[7] = f2bf(b.w);
  *((short8*)out + i) = o;
}

// ---------------------------------------------------------------------------
// C = A * B^T, bf16 MFMA 16x16x32. BM=MREP*32, BN=256, BK=32, 512 threads
// (8 waves 2M x 4N, wave tile MREP*16 x 64). QUAD-buffered LDS; ONE barrier +
// ONE counted vmcnt per K-tile: { vmcnt(2*LPT); barrier; 12 ds_read; stage
// tile t+3 (LPT gloads); 4*MREP MFMA }. Swizzle: 16B slot ^= (row>>1)&3 on
// both stage-source and ds_read (bank = (row&1)*16+slot*4; row bits 1-2 are
// the free entropy -> 2-way max, free per m136).
// MODE 2: C fp32 = acc*scale + rel_bias[gc-gr+ml-1] (scores)
// MODE 3: C fp32 = acc (PV)
// MODE 4: fused QKV: 1024-col slice 0 -> Q bf16, 1 -> K bf16, 2 -> V^T
// ---------------------------------------------------------------------------
template <int MODE, int MREP>
__global__ __launch_bounds__(512) void gemm1b(
    const short* __restrict__ A, const short* __restrict__ Bt,
    void* __restrict__ C0, void* __restrict__ C1, void* __restrict__ C2,
    const float* __restrict__ rel_bias,
    int N, int K, long aZ, long bZ, long cZ, int Cdim, float scale, int ml) {
  constexpr int AROWS = MREP * 32;          // 256 or 128
  __shared__ short sA[4][AROWS * 32];
  __shared__ short sB[4][256 * 32];
  const int tid = threadIdx.x, lane = tid & 63, wid = tid >> 6;
  const int z = blockIdx.z;
  const short* Az = A + (size_t)z * aZ;
  const short* Bz = Bt + (size_t)z * bZ;
  const int brow = blockIdx.x * AROWS, bcol = blockIdx.y * 256;
  const int wr = wid >> 2, wc = wid & 3;
  const int lrow = lane & 15, kg = lane >> 4;

  // staging: wave covers 16 rows (4 lanes/row); swizzled source column
  const int srow = wid * 16 + (lane >> 2);
  const int scol = ((lane & 3) ^ ((lane >> 3) & 3)) * 8;  // slot ^ (row>>1)&3
  const short* aSrc0 = Az + (size_t)(brow + srow) * K + scol;
  const short* aSrc1 = Az + (size_t)(brow + 128 + srow) * K + scol;  // MREP=8 only
  const short* bSrc0 = Bz + (size_t)(bcol + srow) * K + scol;
  const short* bSrc1 = Bz + (size_t)(bcol + 128 + srow) * K + scol;
  const int d0 = wid * 512, d1 = 4096 + wid * 512;  // LDS dest (shorts)

  // ds_read: physical slot = kg ^ ((row>>1)&3); row bits 1-2 == lrow bits 1-2
  const int kOff = (kg ^ ((lrow >> 1) & 3)) * 8;
  const int aBase = (wr * (MREP * 16) + lrow) * 32 + kOff;  // + m*512
  const int bBase = (wc * 64 + lrow) * 32 + kOff;           // + n*512

  short8 a[MREP], b[4];
  f32x4 acc[MREP][4] = {};

  short *pa0 = &sA[0][0], *pa1 = &sA[1][0], *pa2 = &sA[2][0], *pa3 = &sA[3][0];
  short *pb0 = &sB[0][0], *pb1 = &sB[1][0], *pb2 = &sB[2][0], *pb3 = &sB[3][0];

#define STG(PA, PB, T)                                              \
  do {                                                              \
    GLD16(aSrc0 + (size_t)(T) * 32, (PA) + d0);                     \
    if constexpr (MREP == 8) GLD16(aSrc1 + (size_t)(T) * 32, (PA) + d1); \
    GLD16(bSrc0 + (size_t)(T) * 32, (PB) + d0);                     \
    GLD16(bSrc1 + (size_t)(T) * 32, (PB) + d1);                     \
  } while (0)
#define RD_ALL(PA, PB)                                              \
  do {                                                              \
    _Pragma("unroll") for (int m = 0; m < MREP; ++m)                \
        a[m] = *(const short8*)&(PA)[aBase + m * 512];              \
    _Pragma("unroll") for (int n = 0; n < 4; ++n)                   \
        b[n] = *(const short8*)&(PB)[bBase + n * 512];              \
  } while (0)
#define MFMA_ALL()                                                            \
  do {                                                                        \
    __builtin_amdgcn_s_setprio(1);                                            \
    _Pragma("unroll") for (int m = 0; m < MREP; ++m)                          \
        _Pragma("unroll") for (int n = 0; n < 4; ++n)                         \
            acc[m][n] = __builtin_amdgcn_mfma_f32_16x16x32_bf16(              \
                a[m], b[n], acc[m][n], 0, 0, 0);                              \
    __builtin_amdgcn_s_setprio(0);                                            \
  } while (0)
#define VM_MAIN()                                                   \
  do {                                                              \
    if constexpr (MREP == 8)                                        \
      asm volatile("s_waitcnt vmcnt(8)" ::: "memory");              \
    else                                                            \
      asm volatile("s_waitcnt vmcnt(6)" ::: "memory");              \
  } while (0)
#define VM_T1()                                                     \
  do {                                                              \
    if constexpr (MREP == 8)                                        \
      asm volatile("s_waitcnt vmcnt(4)" ::: "memory");              \
    else                                                            \
      asm volatile("s_waitcnt vmcnt(3)" ::: "memory");              \
  } while (0)
#define VM_0() asm volatile("s_waitcnt vmcnt(0)" ::: "memory")
#define ROT()                                                    \
  do {                                                           \
    short* q;                                                    \
    q = pa0; pa0 = pa1; pa1 = pa2; pa2 = pa3; pa3 = q;           \
    q = pb0; pb0 = pb1; pb1 = pb2; pb2 = pb3; pb3 = q;           \
  } while (0)

  // prologue: stage tiles 0,1,2 (3*LPT loads outstanding)
  STG(pa0, pb0, 0);
  STG(pa1, pb1, 1);
  STG(pa2, pb2, 2);

  const int NT = K >> 5;  // K/32 tiles (>= 32 here)
  for (int t = 0; t < NT - 3; ++t) {
    VM_MAIN();  // drain tile t's LPT loads (t+1,t+2,t+3-partial stay in flight)
    BAR();
    RD_ALL(pa0, pb0);
    STG(pa3, pb3, t + 3);
    MFMA_ALL();
    ROT();
  }
  // t = NT-3: no staging
  VM_MAIN(); BAR();
  RD_ALL(pa0, pb0);
  MFMA_ALL();
  ROT();
  // t = NT-2
  VM_T1(); BAR();
  RD_ALL(pa0, pb0);
  MFMA_ALL();
  ROT();
  // t = NT-1
  VM_0(); BAR();
  RD_ALL(pa0, pb0);
  MFMA_ALL();

  // epilogue
#pragma unroll
  for (int m = 0; m < MREP; ++m) {
#pragma unroll
    for (int n = 0; n < 4; ++n) {
#pragma unroll
      for (int r = 0; r < 4; ++r) {
        float v = acc[m][n][r];
        int gr = brow + wr * (MREP * 16) + m * 16 + kg * 4 + r;
        int gc = bcol + wc * 64 + n * 16 + lrow;
        if constexpr (MODE == 2) {
          int idx = gc - gr + (ml - 1);
          idx = min(max(idx, 0), 2 * ml - 2);
          ((float*)C0 + (size_t)z * cZ)[(size_t)gr * N + gc] =
              v * scale + rel_bias[idx];
        } else if constexpr (MODE == 3) {
          ((float*)C0 + (size_t)z * cZ)[(size_t)gr * N + gc] = v;
        } else {  // MODE 4: fused QKV, 1024-col slices
          int s = gc >> 10, cc = gc & 1023;
          if (s == 0) {
            ((short*)C0)[(size_t)gr * 1024 + cc] = f2bf(v);
          } else if (s == 1) {
            ((short*)C1)[(size_t)gr * 1024 + cc] = f2bf(v);
          } else {
            int b_ = gr / Cdim, c_ = gr % Cdim;
            ((short*)C2)[((size_t)b_ * 1024 + cc) * Cdim + c_] = f2bf(v);
          }
        }
      }
    }
  }
#undef STG
#undef RD_ALL
#undef MFMA_ALL
#undef VM_MAIN
#undef VM_T1
#undef VM_0
#undef ROT
}

// Row softmax in place (rows of 2048) + bf16 copy for the PV GEMM.
__global__ __launch_bounds__(256) void softmax_rows(float* __restrict__ w,
                                                    short* __restrict__ wb, int Cd) {
  const size_t row = blockIdx.x;
  float4* p = (float4*)(w + row * (size_t)Cd);
  const int tid = threadIdx.x;
  float4 v0 = p[tid];
  float4 v1 = p[tid + 256];
  float mx = fmaxf(fmaxf(fmaxf(v0.x, v0.y), fmaxf(v0.z, v0.w)),
                   fmaxf(fmaxf(v1.x, v1.y), fmaxf(v1.z, v1.w)));
#pragma unroll
  for (int o = 32; o; o >>= 1) mx = fmaxf(mx, __shfl_xor(mx, o));
  __shared__ float red[8];
  const int wv = tid >> 6;
  if ((tid & 63) == 0) red[wv] = mx;
  __syncthreads();
  mx = fmaxf(fmaxf(red[0], red[1]), fmaxf(red[2], red[3]));
  v0.x = __expf(v0.x - mx); v0.y = __expf(v0.y - mx);
  v0.z = __expf(v0.z - mx); v0.w = __expf(v0.w - mx);
  v1.x = __expf(v1.x - mx); v1.y = __expf(v1.y - mx);
  v1.z = __expf(v1.z - mx); v1.w = __expf(v1.w - mx);
  float s = v0.x + v0.y + v0.z + v0.w + v1.x + v1.y + v1.z + v1.w;
#pragma unroll
  for (int o = 32; o; o >>= 1) s += __shfl_xor(s, o);
  if ((tid & 63) == 0) red[4 + wv] = s;
  __syncthreads();
  s = red[4] + red[5] + red[6] + red[7];
  float inv = 1.0f / s;
  v0.x *= inv; v0.y *= inv; v0.z *= inv; v0.w *= inv;
  v1.x *= inv; v1.y *= inv; v1.z *= inv; v1.w *= inv;
  p[tid] = v0;
  p[tid + 256] = v1;
  short4v b0, b1;
  b0[0] = f2bf(v0.x); b0[1] = f2bf(v0.y); b0[2] = f2bf(v0.z); b0[3] = f2bf(v0.w);
  b1[0] = f2bf(v1.x); b1[1] = f2bf(v1.y); b1[2] = f2bf(v1.z); b1[3] = f2bf(v1.w);
  short* wrow = wb + row * (size_t)Cd;
  *(short4v*)&wrow[tid * 4] = b0;
  *(short4v*)&wrow[1024 + tid * 4] = b1;
}

extern "C" void kernel_launch(void* const* d_in, const int* in_sizes, int n_in,
                              void* d_out, int out_size, void* d_ws, size_t ws_size,
                              hipStream_t stream) {
  const float* x = (const float*)d_in[0];
  const float* Wq = (const float*)d_in[1];
  const float* Wk = (const float*)d_in[2];
  const float* Wv = (const float*)d_in[3];
  const float* rb = (const float*)d_in[4];

  const int E = 1024;
  const int Mt = in_sizes[0] / E;           // B*C = 8192
  const int Cd = out_size / Mt - E;         // 2048
  const int B = Mt / Cd;                    // 4
  const int ml = (in_sizes[4] + 1) / 2;     // max_len = 2048
  const float scale = 1.0f / sqrtf((float)E);

  // workspace layout (bf16 = short)
  short* xb = (short*)d_ws;                 // Mt*E
  short* wqb = xb + (size_t)Mt * E;         // E*E (Wq,Wk,Wv contiguous = 3072xE)
  short* wkb = wqb + (size_t)E * E;
  short* wvb = wkb + (size_t)E * E;
  short* Qb = wvb + (size_t)E * E;          // Mt*E
  short* Kb = Qb + (size_t)Mt * E;          // Mt*E
  short* Vt = Kb + (size_t)Mt * E;          // B*E*Cd
  short* wbf = Qb;                          // Mt*Cd (reuse Q+K after scores)

  float* outp = (float*)d_out;              // Mt*E
  float* wts = outp + (size_t)Mt * E;       // Mt*Cd

  cvt_f32_bf16<<<(Mt * E) / 2048, 256, 0, stream>>>(x, xb, (Mt * E) / 8);
  cvt_f32_bf16<<<(E * E) / 2048, 256, 0, stream>>>(Wq, wqb, (E * E) / 8);
  cvt_f32_bf16<<<(E * E) / 2048, 256, 0, stream>>>(Wk, wkb, (E * E) / 8);
  cvt_f32_bf16<<<(E * E) / 2048, 256, 0, stream>>>(Wv, wvb, (E * E) / 8);

  dim3 blk(512);
  // fused QKV projection: A = xb (8192x1024), Bt = [Wq;Wk;Wv] (3072x1024)
  gemm1b<4, 8><<<dim3(Mt / 256, 3 * E / 256, 1), blk, 0, stream>>>(
      xb, wqb, Qb, Kb, Vt, nullptr, 3 * E, E, 0, 0, 0, Cd, 0.f, ml);
  // scores = Q K^T * scale + bias (fp32 into weights region)
  gemm1b<2, 8><<<dim3(Cd / 256, Cd / 256, B), blk, 0, stream>>>(
      Qb, Kb, wts, nullptr, nullptr, rb, Cd, E, (long)Cd * E, (long)Cd * E,
      (long)Cd * Cd, Cd, scale, ml);
  softmax_rows<<<Mt, 256, 0, stream>>>(wts, wbf, Cd);
  // out = weights @ V (A = bf16 weights, Bt = V^T); BM=128 -> 256 blocks
  gemm1b<3, 4><<<dim3(Cd / 128, E / 256, B), blk, 0, stream>>>(
      wbf, Vt, outp, nullptr, nullptr, nullptr, E, Cd, (long)Cd * Cd,
      (long)E * Cd, (long)Cd * E, Cd, 0.f, ml);
}